// Round 4
// baseline (111.323 us; speedup 1.0000x reference)
//
#include <hip/hip_runtime.h>

// PTS loss: B=32, N=2048.
//   non-sym batch: sum_n ||R_e p_n - R_g p_n||^2
//   sym batch:     sum_n min_m ||R_e p_n - R_g p_m||^2
// out = (sum_s + sum_p) / (2*N*B), single f32 scalar.
//
// R4: single fused kernel. Grid (B, MS). Sym chunk blocks write per-chunk
// partial mins (xx folded in); last-arriving chunk block (per-batch counter
// in ws) min-reduces the MS chunks and writes bsum[b]; last batch overall
// (global counter) sums bsum and stores out (single plain store -> no
// zero-init needed). Counters start at the harness's 0xAA poison pattern;
// detection accepts both 0xAAAAAAAA and 0 bases. __threadfence() around the
// atomics handles cross-XCD visibility (sc1 writeback/invalidate).

#define TPB  256
#define NPTS 2048
#define MS   16           // m-chunks per sym batch
#define MCH  (NPTS / MS)  // 128 candidates per chunk
#define PX   8            // x-points per thread (NPTS / TPB)
#define POISON_U 0xAAAAAAAAu

__device__ __forceinline__ void quat2mat(const float* __restrict__ q, float R[9]) {
    float w = q[0], x = q[1], y = q[2], z = q[3];
    float inv = 1.0f / sqrtf(w*w + x*x + y*y + z*z);
    w *= inv; x *= inv; y *= inv; z *= inv;
    R[0] = 1.f - 2.f*(y*y + z*z); R[1] = 2.f*(x*y - w*z);       R[2] = 2.f*(x*z + w*y);
    R[3] = 2.f*(x*y + w*z);       R[4] = 1.f - 2.f*(x*x + z*z); R[5] = 2.f*(y*z - w*x);
    R[6] = 2.f*(x*z - w*y);       R[7] = 2.f*(y*z + w*x);       R[8] = 1.f - 2.f*(x*x + y*y);
}

__device__ __forceinline__ float block_reduce_add(float v, float* red) {
    #pragma unroll
    for (int off = 32; off > 0; off >>= 1)
        v += __shfl_down(v, off, 64);
    const int tid = threadIdx.x;
    if ((tid & 63) == 0) red[tid >> 6] = v;
    __syncthreads();
    return red[0] + red[1] + red[2] + red[3];
}

// Called by one thread (tid 0) holding this batch's sum. Publishes bsum[b],
// bumps the global batch counter; the last batch sums all bsum -> out.
__device__ __forceinline__ void publish_batch_sum(
    int b, int nB, float s, float* __restrict__ bsum,
    unsigned* __restrict__ gcnt, float* __restrict__ out, float scale)
{
    bsum[b] = s;
    __threadfence();
    unsigned old = atomicAdd(gcnt, 1u);
    if (old == POISON_U + (unsigned)(nB - 1) || old == (unsigned)(nB - 1)) {
        __threadfence();
        float tot = 0.f;
        for (int i = 0; i < nB; ++i) tot += bsum[i];
        *out = tot * scale;
    }
}

__global__ __launch_bounds__(TPB) void pts_loss_fused(
    const float* __restrict__ q_est, const float* __restrict__ q_gt,
    const float* __restrict__ pts, const int* __restrict__ symmetries,
    float* __restrict__ out, float* __restrict__ partial,
    float* __restrict__ bsum, unsigned* __restrict__ bcnt,
    unsigned* __restrict__ gcnt, float scale, int nB)
{
    const int b   = blockIdx.x;
    const int ms  = blockIdx.y;
    const int tid = threadIdx.x;

    __shared__ float4 ybuf[MCH];      // 2 KB
    __shared__ float  red[TPB / 64];
    __shared__ int    last_sh;

    const bool is_sym = symmetries[b] != 0;   // block-uniform
    const float* pb = pts + (size_t)b * NPTS * 3;

    if (!is_sym) {
        if (ms != 0) return;
        float Re[9], Rg[9];
        quat2mat(q_est + 4*b, Re);
        quat2mat(q_gt  + 4*b, Rg);
        float s = 0.f;
        #pragma unroll
        for (int k = 0; k < PX; ++k) {
            int n = k * TPB + tid;
            float p0 = pb[3*n+0], p1 = pb[3*n+1], p2 = pb[3*n+2];
            float d0 = (Re[0]-Rg[0])*p0 + (Re[1]-Rg[1])*p1 + (Re[2]-Rg[2])*p2;
            float d1 = (Re[3]-Rg[3])*p0 + (Re[4]-Rg[4])*p1 + (Re[5]-Rg[5])*p2;
            float d2 = (Re[6]-Rg[6])*p0 + (Re[7]-Rg[7])*p1 + (Re[8]-Rg[8])*p2;
            s += d0*d0 + d1*d1 + d2*d2;
        }
        s = block_reduce_add(s, red);
        if (tid == 0) publish_batch_sum(b, nB, s, bsum, gcnt, out, scale);
        return;
    }

    float Re[9], Rg[9];
    quat2mat(q_est + 4*b, Re);
    quat2mat(q_gt  + 4*b, Rg);

    // stage this block's y-chunk: candidate m = ms*MCH + tid  (tid < MCH)
    if (tid < MCH) {
        int m = ms * MCH + tid;
        float p0 = pb[3*m+0], p1 = pb[3*m+1], p2 = pb[3*m+2];
        float y0 = Rg[0]*p0 + Rg[1]*p1 + Rg[2]*p2;
        float y1 = Rg[3]*p0 + Rg[4]*p1 + Rg[5]*p2;
        float y2 = Rg[6]*p0 + Rg[7]*p1 + Rg[8]*p2;
        ybuf[tid] = make_float4(y0, y1, y2, y0*y0 + y1*y1 + y2*y2);
    }
    __syncthreads();

    // my PX x-points: n = k*TPB + tid (coalesced)
    float nx0[PX], nx1[PX], nx2[PX], xx[PX], mins[PX];
    #pragma unroll
    for (int k = 0; k < PX; ++k) {
        int n = k * TPB + tid;
        float p0 = pb[3*n+0], p1 = pb[3*n+1], p2 = pb[3*n+2];
        float x0 = Re[0]*p0 + Re[1]*p1 + Re[2]*p2;
        float x1 = Re[3]*p0 + Re[4]*p1 + Re[5]*p2;
        float x2 = Re[6]*p0 + Re[7]*p1 + Re[8]*p2;
        nx0[k] = -2.f*x0; nx1[k] = -2.f*x1; nx2[k] = -2.f*x2;
        xx[k]  = x0*x0 + x1*x1 + x2*x2;
        mins[k] = 1e30f;
    }

    // min over this chunk: one broadcast b128 read feeds 8 points (32 VALU)
    #pragma unroll 4
    for (int m = 0; m < MCH; ++m) {
        float4 y = ybuf[m];
        #pragma unroll
        for (int k = 0; k < PX; ++k) {
            float t = fmaf(nx0[k], y.x, fmaf(nx1[k], y.y, fmaf(nx2[k], y.z, y.w)));
            mins[k] = fminf(mins[k], t);
        }
    }

    // publish chunk partial (xx folded in so finalize needs only these)
    float* pp = partial + ((size_t)b * MS + ms) * NPTS;
    #pragma unroll
    for (int k = 0; k < PX; ++k)
        pp[k * TPB + tid] = mins[k] + xx[k];

    __threadfence();          // make my stores device-visible
    __syncthreads();          // all threads' fences done
    if (tid == 0) {
        unsigned old = atomicAdd(&bcnt[b], 1u);
        last_sh = (old == POISON_U + (unsigned)(MS - 1) ||
                   old == (unsigned)(MS - 1));
    }
    __syncthreads();
    if (!last_sh) return;
    __threadfence();          // acquire: invalidate stale L2 lines

    // finalize this batch: min over MS chunks, sum over n
    const float* pbase = partial + (size_t)b * MS * NPTS;
    float s = 0.f;
    #pragma unroll
    for (int k = 0; k < PX; ++k) {
        int n = k * TPB + tid;
        float v = pbase[n];
        #pragma unroll
        for (int c = 1; c < MS; ++c)
            v = fminf(v, pbase[c * NPTS + n]);
        s += v;
    }
    s = block_reduce_add(s, red);
    if (tid == 0) publish_batch_sum(b, nB, s, bsum, gcnt, out, scale);
}

extern "C" void kernel_launch(void* const* d_in, const int* in_sizes, int n_in,
                              void* d_out, int out_size, void* d_ws, size_t ws_size,
                              hipStream_t stream) {
    const float* q_est = (const float*)d_in[0];
    const float* q_gt  = (const float*)d_in[1];
    // d_in[2] = T, unused by the reference
    const float* pts   = (const float*)d_in[3];
    const int*   sym   = (const int*)d_in[4];
    float* out = (float*)d_out;

    const int B = in_sizes[0] / 4;  // 32
    const float scale = 1.0f / (2.0f * (float)NPTS * (float)B);

    float*    partial = (float*)d_ws;                         // B*MS*NPTS = 4 MB
    float*    bsum    = partial + (size_t)B * MS * NPTS;      // B floats
    unsigned* bcnt    = (unsigned*)(bsum + B);                // B uints
    unsigned* gcnt    = bcnt + B;                             // 1 uint

    dim3 grid(B, MS);
    pts_loss_fused<<<grid, TPB, 0, stream>>>(q_est, q_gt, pts, sym, out,
                                             partial, bsum, bcnt, gcnt, scale, B);
}

// Round 5
// 75.004 us; speedup vs baseline: 1.4842x; 1.4842x over previous
//
#include <hip/hip_runtime.h>

// PTS loss: B=32, N=2048.
//   non-sym batch: sum_n ||R_e p_n - R_g p_n||^2
//   sym batch:     sum_n min_m ||R_e p_n - R_g p_m||^2
// out = (sum_s + sum_p) / (2*N*B), single f32 scalar.
//
// R5: revert R4's single-kernel fuse (device-scope __threadfence per block
// cost 56us of stall — cross-XCD release/acquire is far more expensive than
// a kernel boundary). Structure = R3 two-kernel, with xx folded into the
// per-chunk partials (min_chunk + xx; min over chunks == xx + global min),
// deleting the xx_ws array and its write/read.

#define TPB  256
#define NPTS 2048
#define MS   16           // m-chunks per sym batch
#define MCH  (NPTS / MS)  // 128 candidates per chunk
#define PX   8            // x-points per thread (NPTS / TPB)

__device__ __forceinline__ void quat2mat(const float* __restrict__ q, float R[9]) {
    float w = q[0], x = q[1], y = q[2], z = q[3];
    float inv = 1.0f / sqrtf(w*w + x*x + y*y + z*z);
    w *= inv; x *= inv; y *= inv; z *= inv;
    R[0] = 1.f - 2.f*(y*y + z*z); R[1] = 2.f*(x*y - w*z);       R[2] = 2.f*(x*z + w*y);
    R[3] = 2.f*(x*y + w*z);       R[4] = 1.f - 2.f*(x*x + z*z); R[5] = 2.f*(y*z - w*x);
    R[6] = 2.f*(x*z - w*y);       R[7] = 2.f*(y*z + w*x);       R[8] = 1.f - 2.f*(x*x + y*y);
}

__device__ __forceinline__ float block_reduce_add(float v, float* red) {
    #pragma unroll
    for (int off = 32; off > 0; off >>= 1)
        v += __shfl_down(v, off, 64);
    const int tid = threadIdx.x;
    if ((tid & 63) == 0) red[tid >> 6] = v;
    __syncthreads();
    return red[0] + red[1] + red[2] + red[3];
}

__global__ __launch_bounds__(TPB) void pts_loss_A(
    const float* __restrict__ q_est, const float* __restrict__ q_gt,
    const float* __restrict__ pts, const int* __restrict__ symmetries,
    float* __restrict__ out, float* __restrict__ partial,
    float* __restrict__ bsum)
{
    const int b   = blockIdx.x;
    const int ms  = blockIdx.y;
    const int tid = threadIdx.x;

    __shared__ float4 ybuf[MCH];      // 2 KB
    __shared__ float  red[TPB / 64];

    // zero the scalar output: single producer, B reads after kernel boundary
    if (b == 0 && ms == 0 && tid == 0) *out = 0.f;

    const bool is_sym = symmetries[b] != 0;   // block-uniform
    const float* pb = pts + (size_t)b * NPTS * 3;

    if (!is_sym) {
        if (ms != 0) return;
        float Re[9], Rg[9];
        quat2mat(q_est + 4*b, Re);
        quat2mat(q_gt  + 4*b, Rg);
        float s = 0.f;
        #pragma unroll
        for (int k = 0; k < PX; ++k) {
            int n = k * TPB + tid;
            float p0 = pb[3*n+0], p1 = pb[3*n+1], p2 = pb[3*n+2];
            float d0 = (Re[0]-Rg[0])*p0 + (Re[1]-Rg[1])*p1 + (Re[2]-Rg[2])*p2;
            float d1 = (Re[3]-Rg[3])*p0 + (Re[4]-Rg[4])*p1 + (Re[5]-Rg[5])*p2;
            float d2 = (Re[6]-Rg[6])*p0 + (Re[7]-Rg[7])*p1 + (Re[8]-Rg[8])*p2;
            s += d0*d0 + d1*d1 + d2*d2;
        }
        s = block_reduce_add(s, red);
        if (tid == 0) bsum[b] = s;
        return;
    }

    float Re[9], Rg[9];
    quat2mat(q_est + 4*b, Re);
    quat2mat(q_gt  + 4*b, Rg);

    // stage this block's y-chunk: candidate m = ms*MCH + tid  (tid < MCH)
    if (tid < MCH) {
        int m = ms * MCH + tid;
        float p0 = pb[3*m+0], p1 = pb[3*m+1], p2 = pb[3*m+2];
        float y0 = Rg[0]*p0 + Rg[1]*p1 + Rg[2]*p2;
        float y1 = Rg[3]*p0 + Rg[4]*p1 + Rg[5]*p2;
        float y2 = Rg[6]*p0 + Rg[7]*p1 + Rg[8]*p2;
        ybuf[tid] = make_float4(y0, y1, y2, y0*y0 + y1*y1 + y2*y2);
    }
    __syncthreads();

    // my PX x-points: n = k*TPB + tid (coalesced)
    float nx0[PX], nx1[PX], nx2[PX], xx[PX], mins[PX];
    #pragma unroll
    for (int k = 0; k < PX; ++k) {
        int n = k * TPB + tid;
        float p0 = pb[3*n+0], p1 = pb[3*n+1], p2 = pb[3*n+2];
        float x0 = Re[0]*p0 + Re[1]*p1 + Re[2]*p2;
        float x1 = Re[3]*p0 + Re[4]*p1 + Re[5]*p2;
        float x2 = Re[6]*p0 + Re[7]*p1 + Re[8]*p2;
        nx0[k] = -2.f*x0; nx1[k] = -2.f*x1; nx2[k] = -2.f*x2;
        xx[k]  = x0*x0 + x1*x1 + x2*x2;
        mins[k] = 1e30f;
    }

    // min over this chunk: one broadcast b128 read feeds 8 points (32 VALU)
    #pragma unroll 4
    for (int m = 0; m < MCH; ++m) {
        float4 y = ybuf[m];
        #pragma unroll
        for (int k = 0; k < PX; ++k) {
            float t = fmaf(nx0[k], y.x, fmaf(nx1[k], y.y, fmaf(nx2[k], y.z, y.w)));
            mins[k] = fminf(mins[k], t);
        }
    }

    // publish chunk partial with xx folded in
    float* pp = partial + ((size_t)b * MS + ms) * NPTS;
    #pragma unroll
    for (int k = 0; k < PX; ++k)
        pp[k * TPB + tid] = mins[k] + xx[k];
}

__global__ __launch_bounds__(TPB) void pts_loss_B(
    const int* __restrict__ symmetries,
    const float* __restrict__ partial,
    const float* __restrict__ bsum, float* __restrict__ out, float scale)
{
    const int b   = blockIdx.x;
    const int tid = threadIdx.x;
    __shared__ float red[TPB / 64];

    if (symmetries[b] == 0) {
        if (tid == 0) atomicAdd(out, bsum[b] * scale);
        return;
    }

    const float* pb = partial + (size_t)b * MS * NPTS;
    float s = 0.f;
    #pragma unroll
    for (int k = 0; k < PX; ++k) {
        int n = k * TPB + tid;
        float v = pb[n];
        #pragma unroll
        for (int ms = 1; ms < MS; ++ms)
            v = fminf(v, pb[ms * NPTS + n]);
        s += v;
    }
    s = block_reduce_add(s, red);
    if (tid == 0) atomicAdd(out, s * scale);
}

extern "C" void kernel_launch(void* const* d_in, const int* in_sizes, int n_in,
                              void* d_out, int out_size, void* d_ws, size_t ws_size,
                              hipStream_t stream) {
    const float* q_est = (const float*)d_in[0];
    const float* q_gt  = (const float*)d_in[1];
    // d_in[2] = T, unused by the reference
    const float* pts   = (const float*)d_in[3];
    const int*   sym   = (const int*)d_in[4];
    float* out = (float*)d_out;

    const int B = in_sizes[0] / 4;  // 32
    const float scale = 1.0f / (2.0f * (float)NPTS * (float)B);

    float* partial = (float*)d_ws;                       // B*MS*NPTS = 4 MB
    float* bsum    = partial + (size_t)B * MS * NPTS;    // B floats

    dim3 gridA(B, MS);
    pts_loss_A<<<gridA, TPB, 0, stream>>>(q_est, q_gt, pts, sym, out, partial, bsum);
    pts_loss_B<<<B, TPB, 0, stream>>>(sym, partial, bsum, out, scale);
}